// Round 1
// baseline (182.917 us; speedup 1.0000x reference)
//
#include <hip/hip_runtime.h>
#include <hip/hip_bf16.h>
#include <stdint.h>

// Problem constants: T=512, B=32, I=512, H=512
#define T_DIM 512
#define B_DIM 32
#define K_DIM 512     // I
#define H_DIM 512
#define N_DIM 1536    // 3*H
#define M_DIM 16384   // T*B

typedef __bf16 bf16_t;
typedef bf16_t bf16x8 __attribute__((ext_vector_type(8)));
typedef float floatx4 __attribute__((ext_vector_type(4)));

// ---------- fp32 -> bf16 (RNE), 8 elems/thread ----------
__device__ __forceinline__ unsigned int f2bf_bits(float f) {
  uint32_t u = __builtin_bit_cast(uint32_t, f);
  u += 0x7FFFu + ((u >> 16) & 1u);
  return u >> 16;
}

__global__ void convert_bf16_kernel(const float* __restrict__ in,
                                    unsigned short* __restrict__ out, int n) {
  int i = (blockIdx.x * blockDim.x + threadIdx.x) * 8;
  if (i >= n) return;
  const float4* p = (const float4*)(in + i);
  float4 f0 = p[0];
  float4 f1 = p[1];
  uint4 v;
  v.x = f2bf_bits(f0.x) | (f2bf_bits(f0.y) << 16);
  v.y = f2bf_bits(f0.z) | (f2bf_bits(f0.w) << 16);
  v.z = f2bf_bits(f1.x) | (f2bf_bits(f1.y) << 16);
  v.w = f2bf_bits(f1.z) | (f2bf_bits(f1.w) << 16);
  *(uint4*)(out + i) = v;
}

// ---------- bf16 GEMM: C[m][n] = sum_k A[m][k] * Bm[n][k]  (NT) ----------
// A: M x K bf16 row-major (x), Bm: N x K bf16 row-major (W_ih), C: M x N fp32.
// 128x128 tile, BK=32, 4 waves (2x2), each wave 64x64 via 4x4 grid of
// 16x16x32 MFMAs. global_load_lds width-16 staging (m97 structure).
__global__ __launch_bounds__(256) void gemm_bf16_kernel(
    const unsigned short* __restrict__ A, const unsigned short* __restrict__ Bm,
    float* __restrict__ C) {
  __shared__ bf16_t smem[8192];  // [0..4095] A-tile 128x32, [4096..] B-tile 128x32
  const int tid = threadIdx.x;
  const int lane = tid & 63;
  const int w = tid >> 6;
  const int tileM = blockIdx.x * 128;
  const int tileN = blockIdx.y * 128;
  const int waveM = w & 1;
  const int waveN = w >> 1;
  const int lm = lane & 15;
  const int lk = (lane >> 4) * 8;

  floatx4 acc[4][4] = {};

  for (int k0 = 0; k0 < K_DIM; k0 += 32) {
#pragma unroll
    for (int j = 0; j < 2; ++j) {
      // chunk id c in [0,512): 16 bytes each; row = c>>2 (64B rows), kc = c&3
      int c = j * 256 + tid;
      int row = c >> 2;
      int kc = c & 3;
      // wave-uniform LDS base (elements); HW adds lane*16B
      bf16_t* la = smem + (j * 256 + w * 64) * 8;
      const unsigned short* ga = A + (size_t)(tileM + row) * K_DIM + k0 + kc * 8;
      __builtin_amdgcn_global_load_lds(
          (const __attribute__((address_space(1))) unsigned int*)ga,
          (__attribute__((address_space(3))) unsigned int*)la, 16, 0, 0);
      bf16_t* lb = smem + 4096 + (j * 256 + w * 64) * 8;
      const unsigned short* gb = Bm + (size_t)(tileN + row) * K_DIM + k0 + kc * 8;
      __builtin_amdgcn_global_load_lds(
          (const __attribute__((address_space(1))) unsigned int*)gb,
          (__attribute__((address_space(3))) unsigned int*)lb, 16, 0, 0);
    }
    __syncthreads();  // drains vmcnt; LDS tiles ready

    bf16x8 af[4], bfg[4];
#pragma unroll
    for (int i = 0; i < 4; ++i)
      af[i] = *(const bf16x8*)(smem + (waveM * 64 + i * 16 + lm) * 32 + lk);
#pragma unroll
    for (int j = 0; j < 4; ++j)
      bfg[j] = *(const bf16x8*)(smem + 4096 + (waveN * 64 + j * 16 + lm) * 32 + lk);
#pragma unroll
    for (int i = 0; i < 4; ++i)
#pragma unroll
      for (int j = 0; j < 4; ++j)
        acc[i][j] = __builtin_amdgcn_mfma_f32_16x16x32_bf16(af[i], bfg[j],
                                                            acc[i][j], 0, 0, 0);
    __syncthreads();  // all waves done reading before next stage overwrites
  }

  // Epilogue: C/D layout col=lane&15, row=(lane>>4)*4+reg (m89/m91 verified)
  const int row0 = tileM + waveM * 64 + (lane >> 4) * 4;
  const int col0 = tileN + waveN * 64 + lm;
#pragma unroll
  for (int i = 0; i < 4; ++i)
#pragma unroll
    for (int j = 0; j < 4; ++j)
#pragma unroll
      for (int r = 0; r < 4; ++r)
        C[(size_t)(row0 + i * 16 + r) * N_DIM + col0 + j * 16] = acc[i][j][r];
}

// ---------- diagonal GRU scan ----------
__device__ __forceinline__ float fast_sigmoid(float x) {
  float e = __builtin_amdgcn_exp2f(-1.442695041f * x);
  return __builtin_amdgcn_rcpf(1.0f + e);
}
__device__ __forceinline__ float fast_tanh(float x) {
  float e = __builtin_amdgcn_exp2f(2.885390082f * x);  // exp(2x)
  return 1.0f - 2.0f * __builtin_amdgcn_rcpf(e + 1.0f);
}

// 16384 threads: one per (b,h). Depth-16 register prefetch of the 3 gate
// streams to cover ~900-cycle HBM latency at 1 wave/CU.
__global__ __launch_bounds__(64) void indgru_scan_kernel(
    const float* __restrict__ gx, const float* __restrict__ h0,
    const float* __restrict__ w_hh, float* __restrict__ out,
    float* __restrict__ hlast) {
  const int idx = blockIdx.x * 64 + threadIdx.x;  // 0..16383
  const int b = idx >> 9;
  const int h = idx & (H_DIM - 1);
  const float wr = w_hh[h];
  const float wz = w_hh[H_DIM + h];
  const float wn = w_hh[2 * H_DIM + h];
  float hv = h0[idx];

  const float* base = gx + (size_t)b * N_DIM + h;   // t-stride = B*3H = 49152
  float* outp = out + (size_t)b * H_DIM + h;        // t-stride = B*H  = 16384

  constexpr int D = 16;
  float pr[D], pz[D], pn[D];
#pragma unroll
  for (int t = 0; t < D; ++t) {
    const float* p = base + (size_t)t * (B_DIM * N_DIM);
    pr[t] = p[0];
    pz[t] = p[H_DIM];
    pn[t] = p[2 * H_DIM];
  }

  // main loop: t in [0, 496), always prefetch t+D
  for (int t0 = 0; t0 < T_DIM - D; t0 += D) {
#pragma unroll
    for (int s = 0; s < D; ++s) {
      const int t = t0 + s;
      float gr = pr[s], gz = pz[s], gn = pn[s];
      const float* p = base + (size_t)(t + D) * (B_DIM * N_DIM);
      pr[s] = p[0];
      pz[s] = p[H_DIM];
      pn[s] = p[2 * H_DIM];
      float r = fast_sigmoid(gr + wr * hv);
      float z = fast_sigmoid(gz + wz * hv);
      float n = fast_tanh(gn + r * (wn * hv));
      hv = (1.0f - z) * n + z * hv;
      outp[(size_t)t * (B_DIM * H_DIM)] = hv;
    }
  }
  // tail: t in [496, 512), no prefetch
#pragma unroll
  for (int s = 0; s < D; ++s) {
    const int t = T_DIM - D + s;
    float r = fast_sigmoid(pr[s] + wr * hv);
    float z = fast_sigmoid(pz[s] + wz * hv);
    float n = fast_tanh(pn[s] + r * (wn * hv));
    hv = (1.0f - z) * n + z * hv;
    outp[(size_t)t * (B_DIM * H_DIM)] = hv;
  }
  hlast[idx] = hv;
}

extern "C" void kernel_launch(void* const* d_in, const int* in_sizes, int n_in,
                              void* d_out, int out_size, void* d_ws, size_t ws_size,
                              hipStream_t stream) {
  const float* x    = (const float*)d_in[0];   // (T,B,I)  = 8388608
  const float* h0   = (const float*)d_in[1];   // (B,H)    = 16384
  const float* W_ih = (const float*)d_in[2];   // (3H,I)   = 786432
  const float* w_hh = (const float*)d_in[3];   // (3,H)    = 1536

  float* out = (float*)d_out;                       // (T,B,H)
  float* hlast = out + (size_t)T_DIM * B_DIM * H_DIM;  // (1,B,H)

  // workspace layout: xb(bf16) 16 MB | Wb(bf16) 1.5 MB | gx(fp32) 100 MB
  char* ws = (char*)d_ws;
  unsigned short* xb = (unsigned short*)ws;
  unsigned short* Wb = (unsigned short*)(ws + 16777216);
  float* gx = (float*)(ws + 16777216 + 1572864);

  convert_bf16_kernel<<<4096, 256, 0, stream>>>(x, xb, M_DIM * K_DIM);
  convert_bf16_kernel<<<384, 256, 0, stream>>>(W_ih, Wb, N_DIM * K_DIM);

  dim3 grid(M_DIM / 128, N_DIM / 128);  // 128 x 12
  gemm_bf16_kernel<<<grid, 256, 0, stream>>>(xb, Wb, gx);

  indgru_scan_kernel<<<256, 64, 0, stream>>>(gx, h0, w_hh, out, hlast);
}

// Round 2
// 176.474 us; speedup vs baseline: 1.0365x; 1.0365x over previous
//
#include <hip/hip_runtime.h>
#include <hip/hip_bf16.h>
#include <stdint.h>

// Problem constants: T=512, B=32, I=512, H=512
#define T_DIM 512
#define B_DIM 32
#define K_DIM 512     // I
#define H_DIM 512
#define N_DIM 1536    // 3*H
#define M_DIM 16384   // T*B

typedef __bf16 bf16_t;
typedef bf16_t bf16x8 __attribute__((ext_vector_type(8)));
typedef float floatx4 __attribute__((ext_vector_type(4)));

// ---------- fp32 -> bf16 (RNE), 8 elems/thread ----------
__device__ __forceinline__ unsigned int f2bf_bits(float f) {
  uint32_t u = __builtin_bit_cast(uint32_t, f);
  u += 0x7FFFu + ((u >> 16) & 1u);
  return u >> 16;
}

__global__ void convert_bf16_kernel(const float* __restrict__ in,
                                    unsigned short* __restrict__ out, int n) {
  int i = (blockIdx.x * blockDim.x + threadIdx.x) * 8;
  if (i >= n) return;
  const float4* p = (const float4*)(in + i);
  float4 f0 = p[0];
  float4 f1 = p[1];
  uint4 v;
  v.x = f2bf_bits(f0.x) | (f2bf_bits(f0.y) << 16);
  v.y = f2bf_bits(f0.z) | (f2bf_bits(f0.w) << 16);
  v.z = f2bf_bits(f1.x) | (f2bf_bits(f1.y) << 16);
  v.w = f2bf_bits(f1.z) | (f2bf_bits(f1.w) << 16);
  *(uint4*)(out + i) = v;
}

// ---------- bf16 GEMM: C[m][n] = sum_k A[m][k] * Bm[n][k]  (NT) ----------
// A: M x K bf16 row-major (x), Bm: N x K bf16 row-major (W_ih), C: M x N fp32.
// 128x128 tile, BK=64, 4 waves (2x2), each wave 64x64 via 4x4 grid of
// 16x16x32 MFMAs, 2 k-substeps per BK iter.
// LDS layout XOR-swizzled: chunk (row, c) [16B chunks, 8 per 128B row] lives
// at slot row*8 + (c ^ (row&7)). Rows all start at bank 0 (128B stride), the
// swizzle spreads the 16 rows of a fragment read across all 8 bank-groups
// -> 2-way max (free). Source-index swizzle keeps global_load_lds's
// uniform-base+lane*16B destination constraint satisfied.
__global__ __launch_bounds__(256) void gemm_bf16_kernel(
    const unsigned short* __restrict__ A, const unsigned short* __restrict__ Bm,
    float* __restrict__ C) {
  __shared__ bf16_t smem[16384];  // [0..8191] A-tile 128x64, [8192..] B-tile
  const int tid = threadIdx.x;
  const int lane = tid & 63;
  const int w = tid >> 6;
  const int tileM = blockIdx.x * 128;
  const int tileN = blockIdx.y * 128;
  const int waveM = w & 1;
  const int waveN = w >> 1;
  const int lm = lane & 15;
  const int lg = lane >> 4;       // 0..3 k-chunk group

  floatx4 acc[4][4] = {};

  for (int k0 = 0; k0 < K_DIM; k0 += 64) {
#pragma unroll
    for (int j = 0; j < 4; ++j) {
      // slot s in [0,1024): 16B chunks; row = s>>3, cpos = s&7
      int s = j * 256 + tid;
      int row = s >> 3;
      int cpos = s & 7;
      int kc = cpos ^ (row & 7);  // source chunk under swizzle
      // wave-uniform LDS base (elements); HW adds lane*16B
      bf16_t* la = smem + (j * 256 + w * 64) * 8;
      const unsigned short* ga = A + (size_t)(tileM + row) * K_DIM + k0 + kc * 8;
      __builtin_amdgcn_global_load_lds(
          (const __attribute__((address_space(1))) unsigned int*)ga,
          (__attribute__((address_space(3))) unsigned int*)la, 16, 0, 0);
      bf16_t* lb = smem + 8192 + (j * 256 + w * 64) * 8;
      const unsigned short* gb = Bm + (size_t)(tileN + row) * K_DIM + k0 + kc * 8;
      __builtin_amdgcn_global_load_lds(
          (const __attribute__((address_space(1))) unsigned int*)gb,
          (__attribute__((address_space(3))) unsigned int*)lb, 16, 0, 0);
    }
    __syncthreads();  // drains vmcnt; LDS tiles ready

#pragma unroll
    for (int ks = 0; ks < 2; ++ks) {
      bf16x8 af[4], bfg[4];
#pragma unroll
      for (int i = 0; i < 4; ++i) {
        int row = waveM * 64 + i * 16 + lm;
        int c = ks * 4 + lg;
        af[i] = *(const bf16x8*)(smem + row * 64 + (c ^ (row & 7)) * 8);
      }
#pragma unroll
      for (int j = 0; j < 4; ++j) {
        int row = waveN * 64 + j * 16 + lm;
        int c = ks * 4 + lg;
        bfg[j] = *(const bf16x8*)(smem + 8192 + row * 64 + (c ^ (row & 7)) * 8);
      }
#pragma unroll
      for (int i = 0; i < 4; ++i)
#pragma unroll
        for (int j = 0; j < 4; ++j)
          acc[i][j] = __builtin_amdgcn_mfma_f32_16x16x32_bf16(af[i], bfg[j],
                                                              acc[i][j], 0, 0, 0);
    }
    __syncthreads();  // all waves done reading before next stage overwrites
  }

  // Epilogue: C/D layout col=lane&15, row=(lane>>4)*4+reg (m89/m91 verified)
  const int row0 = tileM + waveM * 64 + (lane >> 4) * 4;
  const int col0 = tileN + waveN * 64 + lm;
#pragma unroll
  for (int i = 0; i < 4; ++i)
#pragma unroll
    for (int j = 0; j < 4; ++j)
#pragma unroll
      for (int r = 0; r < 4; ++r)
        C[(size_t)(row0 + i * 16 + r) * N_DIM + col0 + j * 16] = acc[i][j][r];
}

// ---------- diagonal GRU scan ----------
__device__ __forceinline__ float fast_sigmoid(float x) {
  float e = __builtin_amdgcn_exp2f(-1.442695041f * x);
  return __builtin_amdgcn_rcpf(1.0f + e);
}
__device__ __forceinline__ float fast_tanh(float x) {
  float e = __builtin_amdgcn_exp2f(2.885390082f * x);  // exp(2x)
  return 1.0f - 2.0f * __builtin_amdgcn_rcpf(e + 1.0f);
}

// 16384 threads: one per (b,h). Depth-16 register prefetch of the 3 gate
// streams to cover ~900-cycle HBM latency at 1 wave/CU.
__global__ __launch_bounds__(64) void indgru_scan_kernel(
    const float* __restrict__ gx, const float* __restrict__ h0,
    const float* __restrict__ w_hh, float* __restrict__ out,
    float* __restrict__ hlast) {
  const int idx = blockIdx.x * 64 + threadIdx.x;  // 0..16383
  const int b = idx >> 9;
  const int h = idx & (H_DIM - 1);
  const float wr = w_hh[h];
  const float wz = w_hh[H_DIM + h];
  const float wn = w_hh[2 * H_DIM + h];
  float hv = h0[idx];

  const float* base = gx + (size_t)b * N_DIM + h;   // t-stride = B*3H = 49152
  float* outp = out + (size_t)b * H_DIM + h;        // t-stride = B*H  = 16384

  constexpr int D = 16;
  float pr[D], pz[D], pn[D];
#pragma unroll
  for (int t = 0; t < D; ++t) {
    const float* p = base + (size_t)t * (B_DIM * N_DIM);
    pr[t] = p[0];
    pz[t] = p[H_DIM];
    pn[t] = p[2 * H_DIM];
  }

  // main loop: t in [0, 496), always prefetch t+D
  for (int t0 = 0; t0 < T_DIM - D; t0 += D) {
#pragma unroll
    for (int s = 0; s < D; ++s) {
      const int t = t0 + s;
      float gr = pr[s], gz = pz[s], gn = pn[s];
      const float* p = base + (size_t)(t + D) * (B_DIM * N_DIM);
      pr[s] = p[0];
      pz[s] = p[H_DIM];
      pn[s] = p[2 * H_DIM];
      float r = fast_sigmoid(gr + wr * hv);
      float z = fast_sigmoid(gz + wz * hv);
      float n = fast_tanh(gn + r * (wn * hv));
      hv = (1.0f - z) * n + z * hv;
      outp[(size_t)t * (B_DIM * H_DIM)] = hv;
    }
  }
  // tail: t in [496, 512), no prefetch
#pragma unroll
  for (int s = 0; s < D; ++s) {
    const int t = T_DIM - D + s;
    float r = fast_sigmoid(pr[s] + wr * hv);
    float z = fast_sigmoid(pz[s] + wz * hv);
    float n = fast_tanh(pn[s] + r * (wn * hv));
    hv = (1.0f - z) * n + z * hv;
    outp[(size_t)t * (B_DIM * H_DIM)] = hv;
  }
  hlast[idx] = hv;
}

extern "C" void kernel_launch(void* const* d_in, const int* in_sizes, int n_in,
                              void* d_out, int out_size, void* d_ws, size_t ws_size,
                              hipStream_t stream) {
  const float* x    = (const float*)d_in[0];   // (T,B,I)  = 8388608
  const float* h0   = (const float*)d_in[1];   // (B,H)    = 16384
  const float* W_ih = (const float*)d_in[2];   // (3H,I)   = 786432
  const float* w_hh = (const float*)d_in[3];   // (3,H)    = 1536

  float* out = (float*)d_out;                       // (T,B,H)
  float* hlast = out + (size_t)T_DIM * B_DIM * H_DIM;  // (1,B,H)

  // workspace layout: xb(bf16) 16 MB | Wb(bf16) 1.5 MB | gx(fp32) 100 MB
  char* ws = (char*)d_ws;
  unsigned short* xb = (unsigned short*)ws;
  unsigned short* Wb = (unsigned short*)(ws + 16777216);
  float* gx = (float*)(ws + 16777216 + 1572864);

  convert_bf16_kernel<<<4096, 256, 0, stream>>>(x, xb, M_DIM * K_DIM);
  convert_bf16_kernel<<<384, 256, 0, stream>>>(W_ih, Wb, N_DIM * K_DIM);

  dim3 grid(M_DIM / 128, N_DIM / 128);  // 128 x 12
  gemm_bf16_kernel<<<grid, 256, 0, stream>>>(xb, Wb, gx);

  indgru_scan_kernel<<<256, 64, 0, stream>>>(gx, h0, w_hh, out, hlast);
}

// Round 3
// 172.273 us; speedup vs baseline: 1.0618x; 1.0244x over previous
//
#include <hip/hip_runtime.h>
#include <hip/hip_bf16.h>
#include <stdint.h>

// Problem constants: T=512, B=32, I=512, H=512
#define T_DIM 512
#define B_DIM 32
#define K_DIM 512     // I
#define H_DIM 512
#define N_DIM 1536    // 3*H
#define M_DIM 16384   // T*B

typedef __bf16 bf16_t;
typedef bf16_t bf16x8 __attribute__((ext_vector_type(8)));
typedef float floatx4 __attribute__((ext_vector_type(4)));

#define LOG2E 1.442695041f     // 1/ln(2)
#define TWO_LOG2E 2.885390082f

// ---------- fp32 -> bf16 (RNE), 8 elems/thread, both inputs fused ----------
__device__ __forceinline__ unsigned int f2bf_bits(float f) {
  uint32_t u = __builtin_bit_cast(uint32_t, f);
  u += 0x7FFFu + ((u >> 16) & 1u);
  return u >> 16;
}

__global__ void convert_both_kernel(const float* __restrict__ x,
                                    unsigned short* __restrict__ xb,
                                    const float* __restrict__ W,
                                    unsigned short* __restrict__ Wb) {
  int bid = blockIdx.x;
  const float* in;
  unsigned short* out;
  int i;
  if (bid < 4096) {           // x: 8388608 elems = 4096 blocks
    in = x; out = xb; i = (bid * 256 + threadIdx.x) * 8;
  } else {                    // W_ih: 786432 elems = 384 blocks
    in = W; out = Wb; i = ((bid - 4096) * 256 + threadIdx.x) * 8;
  }
  const float4* p = (const float4*)(in + i);
  float4 f0 = p[0];
  float4 f1 = p[1];
  uint4 v;
  v.x = f2bf_bits(f0.x) | (f2bf_bits(f0.y) << 16);
  v.y = f2bf_bits(f0.z) | (f2bf_bits(f0.w) << 16);
  v.z = f2bf_bits(f1.x) | (f2bf_bits(f1.y) << 16);
  v.w = f2bf_bits(f1.z) | (f2bf_bits(f1.w) << 16);
  *(uint4*)(out + i) = v;
}

// ---------- bf16 GEMM: C[m][n] = scale(n) * sum_k A[m][k] * Bm[n][k] ----------
// A: M x K bf16 row-major (x), Bm: N x K bf16 row-major (W_ih), C: M x N fp32.
// 128x128 tile, BK=64, 4 waves (2x2), each wave 64x64 via 4x4 grid of
// 16x16x32 MFMAs, 2 k-substeps per BK iter. XOR-swizzled LDS (R2, conflict-free).
// Epilogue pre-scales gate pre-activations for the scan: cols [0,1024) (r,z)
// by -log2(e) [sigmoid via exp2], cols [1024,1536) (n) by +2*log2(e) [tanh].
__global__ __launch_bounds__(256) void gemm_bf16_kernel(
    const unsigned short* __restrict__ A, const unsigned short* __restrict__ Bm,
    float* __restrict__ C) {
  __shared__ bf16_t smem[16384];  // [0..8191] A-tile 128x64, [8192..] B-tile
  const int tid = threadIdx.x;
  const int lane = tid & 63;
  const int w = tid >> 6;
  const int tileM = blockIdx.x * 128;
  const int tileN = blockIdx.y * 128;
  const int waveM = w & 1;
  const int waveN = w >> 1;
  const int lm = lane & 15;
  const int lg = lane >> 4;       // 0..3 k-chunk group

  floatx4 acc[4][4] = {};

  for (int k0 = 0; k0 < K_DIM; k0 += 64) {
#pragma unroll
    for (int j = 0; j < 4; ++j) {
      // slot s in [0,1024): 16B chunks; row = s>>3, cpos = s&7
      int s = j * 256 + tid;
      int row = s >> 3;
      int cpos = s & 7;
      int kc = cpos ^ (row & 7);  // source chunk under swizzle
      bf16_t* la = smem + (j * 256 + w * 64) * 8;
      const unsigned short* ga = A + (size_t)(tileM + row) * K_DIM + k0 + kc * 8;
      __builtin_amdgcn_global_load_lds(
          (const __attribute__((address_space(1))) unsigned int*)ga,
          (__attribute__((address_space(3))) unsigned int*)la, 16, 0, 0);
      bf16_t* lb = smem + 8192 + (j * 256 + w * 64) * 8;
      const unsigned short* gb = Bm + (size_t)(tileN + row) * K_DIM + k0 + kc * 8;
      __builtin_amdgcn_global_load_lds(
          (const __attribute__((address_space(1))) unsigned int*)gb,
          (__attribute__((address_space(3))) unsigned int*)lb, 16, 0, 0);
    }
    __syncthreads();

#pragma unroll
    for (int ks = 0; ks < 2; ++ks) {
      bf16x8 af[4], bfg[4];
#pragma unroll
      for (int i = 0; i < 4; ++i) {
        int row = waveM * 64 + i * 16 + lm;
        int c = ks * 4 + lg;
        af[i] = *(const bf16x8*)(smem + row * 64 + (c ^ (row & 7)) * 8);
      }
#pragma unroll
      for (int j = 0; j < 4; ++j) {
        int row = waveN * 64 + j * 16 + lm;
        int c = ks * 4 + lg;
        bfg[j] = *(const bf16x8*)(smem + 8192 + row * 64 + (c ^ (row & 7)) * 8);
      }
#pragma unroll
      for (int i = 0; i < 4; ++i)
#pragma unroll
        for (int j = 0; j < 4; ++j)
          acc[i][j] = __builtin_amdgcn_mfma_f32_16x16x32_bf16(af[i], bfg[j],
                                                              acc[i][j], 0, 0, 0);
    }
    __syncthreads();
  }

  // Epilogue: C/D layout col=lane&15, row=(lane>>4)*4+reg (m89/m91 verified)
  const int row0 = tileM + waveM * 64 + (lane >> 4) * 4;
  const int col0 = tileN + waveN * 64 + lm;
#pragma unroll
  for (int i = 0; i < 4; ++i)
#pragma unroll
    for (int j = 0; j < 4; ++j) {
      const int col = col0 + j * 16;
      const float scl = (col >= 2 * H_DIM) ? TWO_LOG2E : -LOG2E;
#pragma unroll
      for (int r = 0; r < 4; ++r)
        C[(size_t)(row0 + i * 16 + r) * N_DIM + col] = scl * acc[i][j][r];
    }
}

// ---------- diagonal GRU scan ----------
// gx pre-scaled: gr' = -log2e*gr, gz' = -log2e*gz, gn' = 2*log2e*gn.
// sigmoid(x) = rcp(1 + exp2(-log2e*x)); tanh(y) = 1 - 2*rcp(exp2(2*log2e*y)+1).
// Critical path per step: fma(ar) exp add rcp fma(an) exp add rcp fma(n) fma(h')
// ~60 cy; z-chain, prefetch, store run in the bubbles.
__global__ __launch_bounds__(64) void indgru_scan_kernel(
    const float* __restrict__ gx, const float* __restrict__ h0,
    const float* __restrict__ w_hh, float* __restrict__ out,
    float* __restrict__ hlast) {
  const int idx = blockIdx.x * 64 + threadIdx.x;  // 0..16383
  const int b = idx >> 9;
  const int h = idx & (H_DIM - 1);
  const float wr = -LOG2E * w_hh[h];
  const float wz = -LOG2E * w_hh[H_DIM + h];
  const float wn = TWO_LOG2E * w_hh[2 * H_DIM + h];
  float hv = h0[idx];

  // base points at the z-plane so the 3 gate loads use imm offsets
  // -2048 / 0 / +2048 bytes (13-bit signed range).
  const float* base = gx + (size_t)b * N_DIM + H_DIM + h;  // t-stride = 49152
  float* outp = out + (size_t)b * H_DIM + h;               // t-stride = 16384

  constexpr int D = 16;
  float pr[D], pz[D], pn[D];
#pragma unroll
  for (int t = 0; t < D; ++t) {
    const float* p = base + (size_t)t * (B_DIM * N_DIM);
    pr[t] = p[-H_DIM];
    pz[t] = p[0];
    pn[t] = p[H_DIM];
  }

  for (int t0 = 0; t0 < T_DIM - D; t0 += D) {
#pragma unroll
    for (int s = 0; s < D; ++s) {
      const int t = t0 + s;
      float gr = pr[s], gz = pz[s], gn = pn[s];
      const float* p = base + (size_t)(t + D) * (B_DIM * N_DIM);
      pr[s] = p[-H_DIM];
      pz[s] = p[0];
      pn[s] = p[H_DIM];
      float ar = fmaf(wr, hv, gr);            // -log2e*(gr + wr*h)
      float az = fmaf(wz, hv, gz);
      float t1 = wn * hv;                     // off critical path
      float er = __builtin_amdgcn_exp2f(ar);
      float ez = __builtin_amdgcn_exp2f(az);
      float r = __builtin_amdgcn_rcpf(1.0f + er);
      float z = __builtin_amdgcn_rcpf(1.0f + ez);
      float en = __builtin_amdgcn_exp2f(fmaf(r, t1, gn));
      float u = __builtin_amdgcn_rcpf(1.0f + en);
      float n = fmaf(-2.0f, u, 1.0f);         // tanh
      float zh = z * hv;                      // z-chain (parallel)
      float omz = 1.0f - z;
      hv = fmaf(n, omz, zh);
      outp[(size_t)t * (B_DIM * H_DIM)] = hv;
    }
  }
#pragma unroll
  for (int s = 0; s < D; ++s) {
    const int t = T_DIM - D + s;
    float ar = fmaf(wr, hv, pr[s]);
    float az = fmaf(wz, hv, pz[s]);
    float t1 = wn * hv;
    float er = __builtin_amdgcn_exp2f(ar);
    float ez = __builtin_amdgcn_exp2f(az);
    float r = __builtin_amdgcn_rcpf(1.0f + er);
    float z = __builtin_amdgcn_rcpf(1.0f + ez);
    float en = __builtin_amdgcn_exp2f(fmaf(r, t1, pn[s]));
    float u = __builtin_amdgcn_rcpf(1.0f + en);
    float n = fmaf(-2.0f, u, 1.0f);
    float zh = z * hv;
    float omz = 1.0f - z;
    hv = fmaf(n, omz, zh);
    outp[(size_t)t * (B_DIM * H_DIM)] = hv;
  }
  hlast[idx] = hv;
}

extern "C" void kernel_launch(void* const* d_in, const int* in_sizes, int n_in,
                              void* d_out, int out_size, void* d_ws, size_t ws_size,
                              hipStream_t stream) {
  const float* x    = (const float*)d_in[0];   // (T,B,I)  = 8388608
  const float* h0   = (const float*)d_in[1];   // (B,H)    = 16384
  const float* W_ih = (const float*)d_in[2];   // (3H,I)   = 786432
  const float* w_hh = (const float*)d_in[3];   // (3,H)    = 1536

  float* out = (float*)d_out;                          // (T,B,H)
  float* hlast = out + (size_t)T_DIM * B_DIM * H_DIM;  // (1,B,H)

  // workspace layout: xb(bf16) 16 MB | Wb(bf16) 1.5 MB | gx(fp32) 100 MB
  char* ws = (char*)d_ws;
  unsigned short* xb = (unsigned short*)ws;
  unsigned short* Wb = (unsigned short*)(ws + 16777216);
  float* gx = (float*)(ws + 16777216 + 1572864);

  convert_both_kernel<<<4480, 256, 0, stream>>>(x, xb, W_ih, Wb);

  dim3 grid(M_DIM / 128, N_DIM / 128);  // 128 x 12
  gemm_bf16_kernel<<<grid, 256, 0, stream>>>(xb, Wb, gx);

  indgru_scan_kernel<<<256, 64, 0, stream>>>(gx, h0, w_hh, out, hlast);
}